// Round 14
// baseline (210.363 us; speedup 1.0000x reference)
//
#include <hip/hip_runtime.h>
#include <cstdint>
#include <cstddef>

#define D_MODEL 1024
#define NH 16
#define DK 64
#define S_LEN 2048
// M = B*S = 4096; QKV packed N = 3072

typedef __attribute__((ext_vector_type(8))) short bf16x8;
typedef __attribute__((ext_vector_type(4))) float f32x4;

#define QSCALE 0.1803368801111204f   // 0.125 * log2(e): exp2-domain softmax

__device__ __forceinline__ unsigned short f2bf(float f) {
    union { float f; unsigned int u; } v; v.f = f;
    unsigned int r = (v.u + 0x7fffu + ((v.u >> 16) & 1u)) >> 16;
    return (unsigned short)r;
}

// async global->LDS, 16B per lane; LDS dst is wave-uniform base + lane*16
#define GLL(g, l) __builtin_amdgcn_global_load_lds( \
    (const __attribute__((address_space(1))) unsigned int*)(g), \
    (__attribute__((address_space(3))) unsigned int*)(l), 16, 0, 0)

// ---------------------------------------------------------------------------
// Pre-pass: fp32 -> bf16 for x and all weights.
// ---------------------------------------------------------------------------
__global__ __launch_bounds__(256) void convert_bf16(
    const float* __restrict__ x,
    const float* __restrict__ wq, const float* __restrict__ wk,
    const float* __restrict__ wv, const float* __restrict__ wo,
    unsigned short* __restrict__ Xb, unsigned short* __restrict__ Wb,
    unsigned short* __restrict__ Wob)
{
    const unsigned t = blockIdx.x * 256 + threadIdx.x;  // float4 index
    const float* src;
    unsigned short* dst;
    if (t < 1048576u)      { src = x  + 4 * (size_t)t;               dst = Xb  + 4 * (size_t)t; }
    else if (t < 1310720u) { size_t i = t - 1048576u; src = wq + 4*i; dst = Wb + 4*i; }
    else if (t < 1572864u) { size_t i = t - 1310720u; src = wk + 4*i; dst = Wb + 1048576u + 4*i; }
    else if (t < 1835008u) { size_t i = t - 1572864u; src = wv + 4*i; dst = Wb + 2097152u + 4*i; }
    else                   { size_t i = t - 1835008u; src = wo + 4*i; dst = Wob + 4*i; }
    float4 v = *(const float4*)src;
    unsigned short pk[4] = {f2bf(v.x), f2bf(v.y), f2bf(v.z), f2bf(v.w)};
    *(uint2*)dst = *(const uint2*)pk;
}

// ---------------------------------------------------------------------------
// MFMA bf16 GEMM, 128x128 tile, BK=64, 256 thr, double-buffered LDS +
// vmcnt(8) (waits only on loads issued a full iteration earlier).
// XOR-swizzled pitch-64 layout; frag reads un-swizzle with ^(m16&7).
// ---------------------------------------------------------------------------

#define CP 132   // Cs pitch: 264 B = 66 dw
__global__ __launch_bounds__(256) void gemm_qkv(
    const unsigned short* __restrict__ Xb, const unsigned short* __restrict__ Wb,
    const float* __restrict__ cosT, const float* __restrict__ sinT,
    const int* __restrict__ posArr,
    unsigned short* __restrict__ Qo, unsigned short* __restrict__ Ko,
    unsigned short* __restrict__ Vt)
{
    __shared__ __align__(16) unsigned short smem[4 * 128 * 64];  // 64 KB
    unsigned short* Cs = smem;   // epilogue overlay

    const int tid  = threadIdx.x;
    const int wave = tid >> 6;
    const int lane = tid & 63;
    const int m16  = lane & 15;
    const int quad = lane >> 4;
    const int warpM = (wave >> 1) * 64;
    const int warpN = (wave & 1) * 64;
    const int rowBase = blockIdx.y * 128;
    const int colBase = blockIdx.x * 128;

    const int l8  = lane >> 3;
    const int lb  = lane & 7;
    const int cbl = (lb ^ l8) * 8;

    const unsigned short* Arow = Xb + (size_t)rowBase * D_MODEL;
    const unsigned short* Brow = Wb + (size_t)colBase * D_MODEL;

    f32x4 acc[4][4];
#pragma unroll
    for (int i = 0; i < 4; ++i)
#pragma unroll
        for (int j = 0; j < 4; ++j) acc[i][j] = (f32x4){0.f, 0.f, 0.f, 0.f};

    auto stage = [&](int k0, int bsel) {
        unsigned short* As = smem + bsel * 16384;
        unsigned short* Bs = As + 8192;
#pragma unroll
        for (int it = 0; it < 4; ++it) {
            const int r = wave * 32 + it * 8 + l8;
            const int dstOff = wave * 2048 + it * 512 + lane * 8;
            GLL(Arow + (size_t)r * D_MODEL + k0 + cbl, &As[dstOff]);
            GLL(Brow + (size_t)r * D_MODEL + k0 + cbl, &Bs[dstOff]);
        }
    };

    stage(0, 0);
    for (int it = 0; it < 16; ++it) {
        const int cur = it & 1;
        if (it < 15) {
            stage((it + 1) * 64, cur ^ 1);
            __asm__ volatile("s_waitcnt vmcnt(8)" ::: "memory");
        } else {
            __asm__ volatile("s_waitcnt vmcnt(0)" ::: "memory");
        }
        __syncthreads();
        const unsigned short* As = smem + cur * 16384;
        const unsigned short* Bs = As + 8192;
#pragma unroll
        for (int ks = 0; ks < 2; ++ks) {
            bf16x8 af[4], bf[4];
#pragma unroll
            for (int t4 = 0; t4 < 4; ++t4) {
                const int rowA = warpM + t4 * 16 + m16;
                const int rowB = warpN + t4 * 16 + m16;
                const int cb = ((ks * 4 + quad) ^ (m16 & 7)) * 8;
                af[t4] = *(const bf16x8*)&As[rowA * 64 + cb];
                bf[t4] = *(const bf16x8*)&Bs[rowB * 64 + cb];
            }
#pragma unroll
            for (int mt = 0; mt < 4; ++mt)
#pragma unroll
                for (int nt = 0; nt < 4; ++nt)
                    acc[mt][nt] = __builtin_amdgcn_mfma_f32_16x16x32_bf16(
                        af[mt], bf[nt], acc[mt][nt], 0, 0, 0);
        }
        __syncthreads();
    }

    const int which = (colBase + warpN) >> 10;   // 0=q,1=k,2=v
    if (which == 2) {
#pragma unroll
        for (int mt = 0; mt < 4; ++mt) {
            const int gr0 = rowBase + warpM + mt * 16 + quad * 4;
            const int b   = gr0 >> 11;
            const int s0  = gr0 & 2047;
#pragma unroll
            for (int nt = 0; nt < 4; ++nt) {
                const int c1 = (colBase + warpN + nt * 16 + m16) & 1023;
                const int h  = c1 >> 6;
                const int d  = c1 & 63;
                unsigned short pk[4];
#pragma unroll
                for (int r = 0; r < 4; ++r) pk[r] = f2bf(acc[mt][nt][r]);
                *(uint2*)(Vt + ((size_t)(b * NH + h) * DK + d) * S_LEN + s0) =
                    *(const uint2*)pk;
            }
        }
    } else {
#pragma unroll
        for (int mt = 0; mt < 4; ++mt) {
            const int lr0 = warpM + mt * 16 + quad * 4;
#pragma unroll
            for (int nt = 0; nt < 4; ++nt) {
                const int lc = warpN + nt * 16 + m16;
                const int d  = lc & 63;
#pragma unroll
                for (int r = 0; r < 4; ++r) {
                    const int s = (rowBase + lr0 + r) & 2047;
                    const int p = posArr[s];
                    float v = acc[mt][nt][r];
                    float o = __shfl_xor(v, 1, 64);
                    float c  = cosT[(size_t)p * DK + d];
                    float sn = sinT[(size_t)p * DK + d];
                    float res = (d & 1) ? (v * c + o * sn) : (v * c - o * sn);
                    if (which == 0) res *= QSCALE;
                    Cs[(lr0 + r) * CP + lc] = f2bf(res);
                }
            }
        }
        __syncthreads();
        unsigned short* outB = (which == 0) ? Qo : Ko;
        const int r2   = tid >> 1;
        const int half = tid & 1;
        const int gr   = rowBase + r2;
        const int b    = gr >> 11;
        const int s    = gr & 2047;
        const int h    = ((colBase & 1023) + half * 64) >> 6;
        unsigned short* dst = outB + ((size_t)(b * NH + h) * S_LEN + s) * DK;
        const unsigned short* srcp = &Cs[r2 * CP + half * 64];
#pragma unroll
        for (int j = 0; j < 8; ++j)
            ((uint4*)dst)[j] = ((const uint4*)srcp)[j];
    }
}

// ---------------------------------------------------------------------------
// Out-projection: C = Ow(4096x1024 bf16) * Wob^T -> fp32 d_out.
// 64x128 tile (M-split) -> grid 512 = 2 blocks/CU. 4 waves as 2(M)x2(N),
// 2x4 acc tiles/wave, dbuf LDS 48 KB, vmcnt(6).
// ---------------------------------------------------------------------------
__global__ __launch_bounds__(256) void gemm_proj(
    const unsigned short* __restrict__ A, const unsigned short* __restrict__ B,
    float* __restrict__ C)
{
    __shared__ __align__(16) unsigned short smem[2 * 12288];  // 48 KB

    const int tid  = threadIdx.x;
    const int wave = tid >> 6;
    const int lane = tid & 63;
    const int m16  = lane & 15;
    const int quad = lane >> 4;
    const int warpM = (wave >> 1) * 32;
    const int warpN = (wave & 1) * 64;
    const int rowBase = blockIdx.y * 64;
    const int colBase = blockIdx.x * 128;

    const int l8  = lane >> 3;
    const int lb  = lane & 7;
    const int cbl = (lb ^ l8) * 8;

    const unsigned short* Arow = A + (size_t)rowBase * D_MODEL;
    const unsigned short* Brow = B + (size_t)colBase * D_MODEL;

    f32x4 acc[2][4];
#pragma unroll
    for (int i = 0; i < 2; ++i)
#pragma unroll
        for (int j = 0; j < 4; ++j) acc[i][j] = (f32x4){0.f, 0.f, 0.f, 0.f};

    auto stage = [&](int k0, int bsel) {
        unsigned short* As = smem + bsel * 12288;   // 64x64
        unsigned short* Bs = As + 4096;             // 128x64
#pragma unroll
        for (int it = 0; it < 2; ++it) {            // A: 2 GLL
            const int r = wave * 16 + it * 8 + l8;
            GLL(Arow + (size_t)r * D_MODEL + k0 + cbl,
                &As[wave * 1024 + it * 512 + lane * 8]);
        }
#pragma unroll
        for (int it = 0; it < 4; ++it) {            // B: 4 GLL
            const int r = wave * 32 + it * 8 + l8;
            GLL(Brow + (size_t)r * D_MODEL + k0 + cbl,
                &Bs[wave * 2048 + it * 512 + lane * 8]);
        }
    };

    stage(0, 0);
    for (int it = 0; it < 16; ++it) {
        const int cur = it & 1;
        if (it < 15) {
            stage((it + 1) * 64, cur ^ 1);
            __asm__ volatile("s_waitcnt vmcnt(6)" ::: "memory");
        } else {
            __asm__ volatile("s_waitcnt vmcnt(0)" ::: "memory");
        }
        __syncthreads();
        const unsigned short* As = smem + cur * 12288;
        const unsigned short* Bs = As + 4096;
#pragma unroll
        for (int ks = 0; ks < 2; ++ks) {
            bf16x8 af[2], bf[4];
            const int cb = ((ks * 4 + quad) ^ (m16 & 7)) * 8;
#pragma unroll
            for (int t4 = 0; t4 < 2; ++t4)
                af[t4] = *(const bf16x8*)&As[(warpM + t4 * 16 + m16) * 64 + cb];
#pragma unroll
            for (int t4 = 0; t4 < 4; ++t4)
                bf[t4] = *(const bf16x8*)&Bs[(warpN + t4 * 16 + m16) * 64 + cb];
#pragma unroll
            for (int mt = 0; mt < 2; ++mt)
#pragma unroll
                for (int nt = 0; nt < 4; ++nt)
                    acc[mt][nt] = __builtin_amdgcn_mfma_f32_16x16x32_bf16(
                        af[mt], bf[nt], acc[mt][nt], 0, 0, 0);
        }
        __syncthreads();
    }

#pragma unroll
    for (int mt = 0; mt < 2; ++mt)
#pragma unroll
        for (int reg = 0; reg < 4; ++reg) {
            int gr = rowBase + warpM + mt * 16 + quad * 4 + reg;
            float* crow = C + (size_t)gr * D_MODEL + colBase + warpN;
#pragma unroll
            for (int nt = 0; nt < 4; ++nt)
                crow[nt * 16 + m16] = acc[mt][nt][reg];
        }
}

// ---------------------------------------------------------------------------
// MFMA flash attention: causal, bf16, exp2-domain (Q pre-scaled), no online
// max. Q-tile 64 (4 waves), K-tile 128, GLL staging, XOR swizzle, l via
// ones-MFMA. P OVERLAYS Ks (Ks is dead after the S-MFMAs; extra barrier
// protects cross-wave Ks reads): LDS 49.4 -> 32 KB, 3 -> 4 blocks/CU.
// P overlay layout: row pitch 128, 16B-chunk swizzle ^(row&15) -> b128 reads
// are 2-way-bank (free), write/read formulas verified to match.
// 1D grid: qt = 31-(g>>5) (big blocks first), bh = g&31 (head-per-XCD L2).
// ---------------------------------------------------------------------------
__global__ __launch_bounds__(256, 4) void flash_mfma(
    const unsigned short* __restrict__ Q,
    const unsigned short* __restrict__ K,
    const unsigned short* __restrict__ Vt,
    unsigned short* __restrict__ O)
{
    const int g    = blockIdx.x;
    const int qt   = 31 - (g >> 5);
    const int bh   = g & 31;
    const int b    = bh >> 4;
    const int h    = bh & 15;
    const int tid  = threadIdx.x;
    const int wave = tid >> 6;
    const int lane = tid & 63;
    const int m16  = lane & 15;
    const int quad = lane >> 4;
    const int l8   = lane >> 3;
    const int nIter = (qt >> 1) + 1;

    __shared__ __align__(16) unsigned short Ks[128 * 64];   // K swz ^(r&7); P overlay
    __shared__ __align__(16) unsigned short VsT[64 * 128];  // [d][s], ^(d&15)
    unsigned short* PsO = Ks;   // P 64x128, pitch 128, chunk swizzle ^(row&15)

    // ---- stage Q tile into Ks rows 0..63 (same swizzle as K), grab frags
    const unsigned short* Qg = Q + ((size_t)bh * S_LEN + qt * 64) * DK;
#pragma unroll
    for (int it = 0; it < 2; ++it) {
        const int rb = wave * 16 + it * 8;
        const int r  = rb + l8;
        const int cb = ((lane & 7) ^ (r & 7)) * 8;
        GLL(Qg + r * DK + cb, &Ks[rb * 64 + lane * 8]);
    }
    __asm__ volatile("s_waitcnt vmcnt(0)" ::: "memory");
    __syncthreads();
    const int qrow = wave * 16 + m16;
    const bf16x8 qf0 = *(const bf16x8*)&Ks[qrow * 64 + ((quad ^ (m16 & 7)) * 8)];
    const bf16x8 qf1 = *(const bf16x8*)&Ks[qrow * 64 + (((4 + quad) ^ (m16 & 7)) * 8)];

    const short one_bf = (short)0x3F80;
    const bf16x8 ones8 = {one_bf, one_bf, one_bf, one_bf,
                          one_bf, one_bf, one_bf, one_bf};

    f32x4 o[4];
    f32x4 lacc = (f32x4){0.f, 0.f, 0.f, 0.f};
#pragma unroll
    for (int r = 0; r < 4; ++r) o[r] = (f32x4){0.f, 0.f, 0.f, 0.f};

    const unsigned short* Kg0 = K + (size_t)bh * S_LEN * DK;
    const unsigned short* Vg0 = Vt + (size_t)bh * DK * S_LEN;

    for (int kb = 0; kb < nIter; ++kb) {
        const int ko = kb * 128;
        __syncthreads();   // prior iter's PV/P reads (and Q preamble) complete
        // K tile: 128 rows x 64 cols, swizzle ^(r&7)
#pragma unroll
        for (int it = 0; it < 4; ++it) {
            const int rb = wave * 32 + it * 8;
            const int r  = rb + l8;
            const int cb = ((lane & 7) ^ (r & 7)) * 8;
            GLL(Kg0 + (size_t)(ko + r) * DK + cb, &Ks[rb * 64 + lane * 8]);
        }
        // V^T tile: 64 rows(d) x 128 cols(s), swizzle ^(d&15)
#pragma unroll
        for (int it = 0; it < 4; ++it) {
            const int db = wave * 16 + it * 4;
            const int d  = db + (lane >> 4);
            const int cb = ((lane & 15) ^ (d & 15)) * 8;
            GLL(Vg0 + (size_t)d * S_LEN + ko + cb, &VsT[db * 128 + lane * 8]);
        }
        __asm__ volatile("s_waitcnt vmcnt(0)" ::: "memory");
        __syncthreads();

        // S = Q*K^T : 16 rows x 128 keys per wave (8 n-tiles)
        f32x4 s[8];
#pragma unroll
        for (int ct = 0; ct < 8; ++ct) {
            const int kr = ct * 16 + m16;
            bf16x8 kf0 = *(const bf16x8*)&Ks[kr * 64 + ((quad ^ (m16 & 7)) * 8)];
            bf16x8 kf1 = *(const bf16x8*)&Ks[kr * 64 + (((4 + quad) ^ (m16 & 7)) * 8)];
            f32x4 z = {0.f, 0.f, 0.f, 0.f};
            z = __builtin_amdgcn_mfma_f32_16x16x32_bf16(qf0, kf0, z, 0, 0, 0);
            z = __builtin_amdgcn_mfma_f32_16x16x32_bf16(qf1, kf1, z, 0, 0, 0);
            s[ct] = z;
        }

        if (kb == nIter - 1) {   // causal mask on the diagonal tile
#pragma unroll
            for (int ct = 0; ct < 8; ++ct)
#pragma unroll
                for (int r = 0; r < 4; ++r) {
                    int colk = ko + ct * 16 + m16;
                    int row  = qt * 64 + wave * 16 + quad * 4 + r;
                    if (colk > row) s[ct][r] = -16384.f;   // exp2 -> 0
                }
        }

        __syncthreads();   // all waves done reading Ks; P overlay may write

        // p = exp2(s); write bf16 P into the Ks overlay (A-layout transform)
#pragma unroll
        for (int ct = 0; ct < 8; ++ct)
#pragma unroll
            for (int r = 0; r < 4; ++r) {
                const int prow = wave * 16 + quad * 4 + r;
                const int chnk = (ct * 2 + (m16 >> 3)) ^ (prow & 15);
                PsO[prow * 128 + chnk * 8 + (m16 & 7)] =
                    f2bf(__builtin_exp2f(s[ct][r]));
            }

        __asm__ volatile("s_waitcnt lgkmcnt(0)" ::: "memory");  // own P visible

        bf16x8 pf[4];
#pragma unroll
        for (int kc = 0; kc < 4; ++kc) {
            const int chnk = (kc * 4 + quad) ^ m16;   // qrow&15 == m16
            pf[kc] = *(const bf16x8*)&PsO[qrow * 128 + chnk * 8];
        }
#pragma unroll
        for (int kc = 0; kc < 4; ++kc)
            lacc = __builtin_amdgcn_mfma_f32_16x16x32_bf16(pf[kc], ones8, lacc, 0, 0, 0);
#pragma unroll
        for (int ct = 0; ct < 4; ++ct) {
            const int vr = ct * 16 + m16;
#pragma unroll
            for (int kc = 0; kc < 4; ++kc) {
                bf16x8 vf = *(const bf16x8*)
                    &VsT[vr * 128 + (((kc * 4 + quad) ^ m16) * 8)];
                o[ct] = __builtin_amdgcn_mfma_f32_16x16x32_bf16(pf[kc], vf, o[ct], 0, 0, 0);
            }
        }
    }

    float inv[4];
#pragma unroll
    for (int r = 0; r < 4; ++r) inv[r] = 1.0f / lacc[r];
#pragma unroll
    for (int r = 0; r < 4; ++r) {
        int srow = qt * 64 + wave * 16 + quad * 4 + r;
        unsigned short* orow = O + (((size_t)b * S_LEN + srow) * NH + h) * DK;
#pragma unroll
        for (int ct = 0; ct < 4; ++ct)
            orow[ct * 16 + m16] = f2bf(o[ct][r] * inv[r]);
    }
}

// ---------------------------------------------------------------------------
extern "C" void kernel_launch(void* const* d_in, const int* in_sizes, int n_in,
                              void* d_out, int out_size, void* d_ws, size_t ws_size,
                              hipStream_t stream)
{
    const float* x      = (const float*)d_in[0];
    const float* Wq     = (const float*)d_in[1];
    const float* Wk     = (const float*)d_in[2];
    const float* Wv     = (const float*)d_in[3];
    const float* Wo     = (const float*)d_in[4];
    const float* cosT   = (const float*)d_in[5];
    const float* sinT   = (const float*)d_in[6];
    const int*   posArr = (const int*)d_in[7];
    float* out = (float*)d_out;

    unsigned short* ws0 = (unsigned short*)d_ws;
    unsigned short* Xb  = ws0;                 // 4,194,304 shorts
    unsigned short* Wb  = ws0 + 4194304;       // 3,145,728 ([Wq;Wk;Wv])
    unsigned short* Wob = ws0 + 7340032;       // 1,048,576
    unsigned short* Qw  = ws0 + 8388608;       // [bh][s][d]
    unsigned short* Kw  = ws0 + 12582912;      // [bh][s][d]
    unsigned short* Vtw = ws0 + 16777216;      // [bh][d][s]
    unsigned short* Ow  = ws0 + 20971520;      // [b][s][h][d]

    convert_bf16<<<8192, 256, 0, stream>>>(x, Wq, Wk, Wv, Wo, Xb, Wb, Wob);

    gemm_qkv<<<dim3(3072 / 128, 4096 / 128), 256, 0, stream>>>(
        Xb, Wb, cosT, sinT, posArr, Qw, Kw, Vtw);

    flash_mfma<<<1024, 256, 0, stream>>>(Qw, Kw, Vtw, Ow);

    gemm_proj<<<dim3(D_MODEL / 128, 4096 / 64), 256, 0, stream>>>(Ow, Wob, out);
}

// Round 15
// 194.869 us; speedup vs baseline: 1.0795x; 1.0795x over previous
//
#include <hip/hip_runtime.h>
#include <cstdint>
#include <cstddef>

#define D_MODEL 1024
#define NH 16
#define DK 64
#define S_LEN 2048
// M = B*S = 4096; QKV packed N = 3072

typedef __attribute__((ext_vector_type(8))) short bf16x8;
typedef __attribute__((ext_vector_type(4))) float f32x4;

#define QSCALE 0.1803368801111204f   // 0.125 * log2(e): exp2-domain softmax

__device__ __forceinline__ unsigned short f2bf(float f) {
    union { float f; unsigned int u; } v; v.f = f;
    unsigned int r = (v.u + 0x7fffu + ((v.u >> 16) & 1u)) >> 16;
    return (unsigned short)r;
}

// async global->LDS, 16B per lane; LDS dst is wave-uniform base + lane*16
#define GLL(g, l) __builtin_amdgcn_global_load_lds( \
    (const __attribute__((address_space(1))) unsigned int*)(g), \
    (__attribute__((address_space(3))) unsigned int*)(l), 16, 0, 0)

// ---------------------------------------------------------------------------
// Pre-pass: fp32 -> bf16 for x and all weights.
// ---------------------------------------------------------------------------
__global__ __launch_bounds__(256) void convert_bf16(
    const float* __restrict__ x,
    const float* __restrict__ wq, const float* __restrict__ wk,
    const float* __restrict__ wv, const float* __restrict__ wo,
    unsigned short* __restrict__ Xb, unsigned short* __restrict__ Wb,
    unsigned short* __restrict__ Wob)
{
    const unsigned t = blockIdx.x * 256 + threadIdx.x;  // float4 index
    const float* src;
    unsigned short* dst;
    if (t < 1048576u)      { src = x  + 4 * (size_t)t;               dst = Xb  + 4 * (size_t)t; }
    else if (t < 1310720u) { size_t i = t - 1048576u; src = wq + 4*i; dst = Wb + 4*i; }
    else if (t < 1572864u) { size_t i = t - 1310720u; src = wk + 4*i; dst = Wb + 1048576u + 4*i; }
    else if (t < 1835008u) { size_t i = t - 1572864u; src = wv + 4*i; dst = Wb + 2097152u + 4*i; }
    else                   { size_t i = t - 1835008u; src = wo + 4*i; dst = Wob + 4*i; }
    float4 v = *(const float4*)src;
    unsigned short pk[4] = {f2bf(v.x), f2bf(v.y), f2bf(v.z), f2bf(v.w)};
    *(uint2*)dst = *(const uint2*)pk;
}

// ---------------------------------------------------------------------------
// MFMA bf16 GEMM, 128x128 tile, BK=64, 256 thr, double-buffered LDS +
// vmcnt(8) (waits only on loads issued a full iteration earlier).
// XOR-swizzled pitch-64 layout; frag reads un-swizzle with ^(m16&7).
// ---------------------------------------------------------------------------

#define CP 132   // Cs pitch: 264 B = 66 dw
__global__ __launch_bounds__(256) void gemm_qkv(
    const unsigned short* __restrict__ Xb, const unsigned short* __restrict__ Wb,
    const float* __restrict__ cosT, const float* __restrict__ sinT,
    const int* __restrict__ posArr,
    unsigned short* __restrict__ Qo, unsigned short* __restrict__ Ko,
    unsigned short* __restrict__ Vt)
{
    __shared__ __align__(16) unsigned short smem[4 * 128 * 64];  // 64 KB
    unsigned short* Cs = smem;   // epilogue overlay

    const int tid  = threadIdx.x;
    const int wave = tid >> 6;
    const int lane = tid & 63;
    const int m16  = lane & 15;
    const int quad = lane >> 4;
    const int warpM = (wave >> 1) * 64;
    const int warpN = (wave & 1) * 64;
    const int rowBase = blockIdx.y * 128;
    const int colBase = blockIdx.x * 128;

    const int l8  = lane >> 3;
    const int lb  = lane & 7;
    const int cbl = (lb ^ l8) * 8;

    const unsigned short* Arow = Xb + (size_t)rowBase * D_MODEL;
    const unsigned short* Brow = Wb + (size_t)colBase * D_MODEL;

    f32x4 acc[4][4];
#pragma unroll
    for (int i = 0; i < 4; ++i)
#pragma unroll
        for (int j = 0; j < 4; ++j) acc[i][j] = (f32x4){0.f, 0.f, 0.f, 0.f};

    auto stage = [&](int k0, int bsel) {
        unsigned short* As = smem + bsel * 16384;
        unsigned short* Bs = As + 8192;
#pragma unroll
        for (int it = 0; it < 4; ++it) {
            const int r = wave * 32 + it * 8 + l8;
            const int dstOff = wave * 2048 + it * 512 + lane * 8;
            GLL(Arow + (size_t)r * D_MODEL + k0 + cbl, &As[dstOff]);
            GLL(Brow + (size_t)r * D_MODEL + k0 + cbl, &Bs[dstOff]);
        }
    };

    stage(0, 0);
    for (int it = 0; it < 16; ++it) {
        const int cur = it & 1;
        if (it < 15) {
            stage((it + 1) * 64, cur ^ 1);
            __asm__ volatile("s_waitcnt vmcnt(8)" ::: "memory");
        } else {
            __asm__ volatile("s_waitcnt vmcnt(0)" ::: "memory");
        }
        __syncthreads();
        const unsigned short* As = smem + cur * 16384;
        const unsigned short* Bs = As + 8192;
#pragma unroll
        for (int ks = 0; ks < 2; ++ks) {
            bf16x8 af[4], bf[4];
#pragma unroll
            for (int t4 = 0; t4 < 4; ++t4) {
                const int rowA = warpM + t4 * 16 + m16;
                const int rowB = warpN + t4 * 16 + m16;
                const int cb = ((ks * 4 + quad) ^ (m16 & 7)) * 8;
                af[t4] = *(const bf16x8*)&As[rowA * 64 + cb];
                bf[t4] = *(const bf16x8*)&Bs[rowB * 64 + cb];
            }
#pragma unroll
            for (int mt = 0; mt < 4; ++mt)
#pragma unroll
                for (int nt = 0; nt < 4; ++nt)
                    acc[mt][nt] = __builtin_amdgcn_mfma_f32_16x16x32_bf16(
                        af[mt], bf[nt], acc[mt][nt], 0, 0, 0);
        }
        __syncthreads();
    }

    const int which = (colBase + warpN) >> 10;   // 0=q,1=k,2=v
    if (which == 2) {
#pragma unroll
        for (int mt = 0; mt < 4; ++mt) {
            const int gr0 = rowBase + warpM + mt * 16 + quad * 4;
            const int b   = gr0 >> 11;
            const int s0  = gr0 & 2047;
#pragma unroll
            for (int nt = 0; nt < 4; ++nt) {
                const int c1 = (colBase + warpN + nt * 16 + m16) & 1023;
                const int h  = c1 >> 6;
                const int d  = c1 & 63;
                unsigned short pk[4];
#pragma unroll
                for (int r = 0; r < 4; ++r) pk[r] = f2bf(acc[mt][nt][r]);
                *(uint2*)(Vt + ((size_t)(b * NH + h) * DK + d) * S_LEN + s0) =
                    *(const uint2*)pk;
            }
        }
    } else {
#pragma unroll
        for (int mt = 0; mt < 4; ++mt) {
            const int lr0 = warpM + mt * 16 + quad * 4;
#pragma unroll
            for (int nt = 0; nt < 4; ++nt) {
                const int lc = warpN + nt * 16 + m16;
                const int d  = lc & 63;
#pragma unroll
                for (int r = 0; r < 4; ++r) {
                    const int s = (rowBase + lr0 + r) & 2047;
                    const int p = posArr[s];
                    float v = acc[mt][nt][r];
                    float o = __shfl_xor(v, 1, 64);
                    float c  = cosT[(size_t)p * DK + d];
                    float sn = sinT[(size_t)p * DK + d];
                    float res = (d & 1) ? (v * c + o * sn) : (v * c - o * sn);
                    if (which == 0) res *= QSCALE;
                    Cs[(lr0 + r) * CP + lc] = f2bf(res);
                }
            }
        }
        __syncthreads();
        unsigned short* outB = (which == 0) ? Qo : Ko;
        const int r2   = tid >> 1;
        const int half = tid & 1;
        const int gr   = rowBase + r2;
        const int b    = gr >> 11;
        const int s    = gr & 2047;
        const int h    = ((colBase & 1023) + half * 64) >> 6;
        unsigned short* dst = outB + ((size_t)(b * NH + h) * S_LEN + s) * DK;
        const unsigned short* srcp = &Cs[r2 * CP + half * 64];
#pragma unroll
        for (int j = 0; j < 8; ++j)
            ((uint4*)dst)[j] = ((const uint4*)srcp)[j];
    }
}

// ---------------------------------------------------------------------------
// Out-projection: C = Ow(4096x1024 bf16) * Wob^T -> fp32 d_out.
// 64x128 tile (M-split) -> grid 512 = 2 blocks/CU. 4 waves as 2(M)x2(N),
// 2x4 acc tiles/wave, dbuf LDS 48 KB, vmcnt(6).
// ---------------------------------------------------------------------------
__global__ __launch_bounds__(256) void gemm_proj(
    const unsigned short* __restrict__ A, const unsigned short* __restrict__ B,
    float* __restrict__ C)
{
    __shared__ __align__(16) unsigned short smem[2 * 12288];  // 48 KB

    const int tid  = threadIdx.x;
    const int wave = tid >> 6;
    const int lane = tid & 63;
    const int m16  = lane & 15;
    const int quad = lane >> 4;
    const int warpM = (wave >> 1) * 32;
    const int warpN = (wave & 1) * 64;
    const int rowBase = blockIdx.y * 64;
    const int colBase = blockIdx.x * 128;

    const int l8  = lane >> 3;
    const int lb  = lane & 7;
    const int cbl = (lb ^ l8) * 8;

    const unsigned short* Arow = A + (size_t)rowBase * D_MODEL;
    const unsigned short* Brow = B + (size_t)colBase * D_MODEL;

    f32x4 acc[2][4];
#pragma unroll
    for (int i = 0; i < 2; ++i)
#pragma unroll
        for (int j = 0; j < 4; ++j) acc[i][j] = (f32x4){0.f, 0.f, 0.f, 0.f};

    auto stage = [&](int k0, int bsel) {
        unsigned short* As = smem + bsel * 12288;   // 64x64
        unsigned short* Bs = As + 4096;             // 128x64
#pragma unroll
        for (int it = 0; it < 2; ++it) {            // A: 2 GLL
            const int r = wave * 16 + it * 8 + l8;
            GLL(Arow + (size_t)r * D_MODEL + k0 + cbl,
                &As[wave * 1024 + it * 512 + lane * 8]);
        }
#pragma unroll
        for (int it = 0; it < 4; ++it) {            // B: 4 GLL
            const int r = wave * 32 + it * 8 + l8;
            GLL(Brow + (size_t)r * D_MODEL + k0 + cbl,
                &Bs[wave * 2048 + it * 512 + lane * 8]);
        }
    };

    stage(0, 0);
    for (int it = 0; it < 16; ++it) {
        const int cur = it & 1;
        if (it < 15) {
            stage((it + 1) * 64, cur ^ 1);
            __asm__ volatile("s_waitcnt vmcnt(6)" ::: "memory");
        } else {
            __asm__ volatile("s_waitcnt vmcnt(0)" ::: "memory");
        }
        __syncthreads();
        const unsigned short* As = smem + cur * 12288;
        const unsigned short* Bs = As + 4096;
#pragma unroll
        for (int ks = 0; ks < 2; ++ks) {
            bf16x8 af[2], bf[4];
            const int cb = ((ks * 4 + quad) ^ (m16 & 7)) * 8;
#pragma unroll
            for (int t4 = 0; t4 < 2; ++t4)
                af[t4] = *(const bf16x8*)&As[(warpM + t4 * 16 + m16) * 64 + cb];
#pragma unroll
            for (int t4 = 0; t4 < 4; ++t4)
                bf[t4] = *(const bf16x8*)&Bs[(warpN + t4 * 16 + m16) * 64 + cb];
#pragma unroll
            for (int mt = 0; mt < 2; ++mt)
#pragma unroll
                for (int nt = 0; nt < 4; ++nt)
                    acc[mt][nt] = __builtin_amdgcn_mfma_f32_16x16x32_bf16(
                        af[mt], bf[nt], acc[mt][nt], 0, 0, 0);
        }
        __syncthreads();
    }

#pragma unroll
    for (int mt = 0; mt < 2; ++mt)
#pragma unroll
        for (int reg = 0; reg < 4; ++reg) {
            int gr = rowBase + warpM + mt * 16 + quad * 4 + reg;
            float* crow = C + (size_t)gr * D_MODEL + colBase + warpN;
#pragma unroll
            for (int nt = 0; nt < 4; ++nt)
                crow[nt * 16 + m16] = acc[mt][nt][reg];
        }
}

// ---------------------------------------------------------------------------
// MFMA flash attention (round-13 version: best measured). Causal, bf16,
// exp2-domain (Q pre-scaled), no online max (scores bounded; uniform exp2
// offsets cancel in o/l). Q-tile 64 (4 waves), K-tile 128, GLL staging,
// XOR swizzle, l via ones-MFMA, separate Ps buffer (49.4 KB LDS, 3 blocks/CU
// — NOT the 32 KB overlay: launch_bounds(256,4) drove VGPR to 64 and spilled
// 50 MB to scratch, r14 regression).
// 1D grid: qt = 31-(g>>5) (big blocks first), bh = g&31 (head-per-XCD L2).
// ---------------------------------------------------------------------------
__global__ __launch_bounds__(256, 3) void flash_mfma(
    const unsigned short* __restrict__ Q,
    const unsigned short* __restrict__ K,
    const unsigned short* __restrict__ Vt,
    unsigned short* __restrict__ O)
{
    const int g    = blockIdx.x;
    const int qt   = 31 - (g >> 5);
    const int bh   = g & 31;
    const int b    = bh >> 4;
    const int h    = bh & 15;
    const int tid  = threadIdx.x;
    const int wave = tid >> 6;
    const int lane = tid & 63;
    const int m16  = lane & 15;
    const int quad = lane >> 4;
    const int l8   = lane >> 3;
    const int nIter = (qt >> 1) + 1;

    __shared__ __align__(16) unsigned short Ks[128 * 64];   // swizzled ^(r&7)
    __shared__ __align__(16) unsigned short VsT[64 * 128];  // [d][s], ^(d&15)
    __shared__ __align__(16) unsigned short Ps[64][136];

    // ---- stage Q tile into Ks rows 0..63 (same swizzle as K), grab frags
    const unsigned short* Qg = Q + ((size_t)bh * S_LEN + qt * 64) * DK;
#pragma unroll
    for (int it = 0; it < 2; ++it) {
        const int rb = wave * 16 + it * 8;
        const int r  = rb + l8;
        const int cb = ((lane & 7) ^ (r & 7)) * 8;
        GLL(Qg + r * DK + cb, &Ks[rb * 64 + lane * 8]);
    }
    __asm__ volatile("s_waitcnt vmcnt(0)" ::: "memory");
    __syncthreads();
    const int qrow = wave * 16 + m16;
    const bf16x8 qf0 = *(const bf16x8*)&Ks[qrow * 64 + ((quad ^ (m16 & 7)) * 8)];
    const bf16x8 qf1 = *(const bf16x8*)&Ks[qrow * 64 + (((4 + quad) ^ (m16 & 7)) * 8)];

    const short one_bf = (short)0x3F80;
    const bf16x8 ones8 = {one_bf, one_bf, one_bf, one_bf,
                          one_bf, one_bf, one_bf, one_bf};

    f32x4 o[4];
    f32x4 lacc = (f32x4){0.f, 0.f, 0.f, 0.f};
#pragma unroll
    for (int r = 0; r < 4; ++r) o[r] = (f32x4){0.f, 0.f, 0.f, 0.f};

    const unsigned short* Kg0 = K + (size_t)bh * S_LEN * DK;
    const unsigned short* Vg0 = Vt + (size_t)bh * DK * S_LEN;

    for (int kb = 0; kb < nIter; ++kb) {
        const int ko = kb * 128;
        __syncthreads();   // prior iter's frag reads (and Q preamble) complete
        // K tile: 128 rows x 64 cols, swizzle ^(r&7)
#pragma unroll
        for (int it = 0; it < 4; ++it) {
            const int rb = wave * 32 + it * 8;
            const int r  = rb + l8;
            const int cb = ((lane & 7) ^ (r & 7)) * 8;
            GLL(Kg0 + (size_t)(ko + r) * DK + cb, &Ks[rb * 64 + lane * 8]);
        }
        // V^T tile: 64 rows(d) x 128 cols(s), swizzle ^(d&15)
#pragma unroll
        for (int it = 0; it < 4; ++it) {
            const int db = wave * 16 + it * 4;
            const int d  = db + (lane >> 4);
            const int cb = ((lane & 15) ^ (d & 15)) * 8;
            GLL(Vg0 + (size_t)d * S_LEN + ko + cb, &VsT[db * 128 + lane * 8]);
        }
        __asm__ volatile("s_waitcnt vmcnt(0)" ::: "memory");
        __syncthreads();

        // S = Q*K^T : 16 rows x 128 keys per wave (8 n-tiles)
        f32x4 s[8];
#pragma unroll
        for (int ct = 0; ct < 8; ++ct) {
            const int kr = ct * 16 + m16;
            bf16x8 kf0 = *(const bf16x8*)&Ks[kr * 64 + ((quad ^ (m16 & 7)) * 8)];
            bf16x8 kf1 = *(const bf16x8*)&Ks[kr * 64 + (((4 + quad) ^ (m16 & 7)) * 8)];
            f32x4 z = {0.f, 0.f, 0.f, 0.f};
            z = __builtin_amdgcn_mfma_f32_16x16x32_bf16(qf0, kf0, z, 0, 0, 0);
            z = __builtin_amdgcn_mfma_f32_16x16x32_bf16(qf1, kf1, z, 0, 0, 0);
            s[ct] = z;
        }

        if (kb == nIter - 1) {   // causal mask on the diagonal tile
#pragma unroll
            for (int ct = 0; ct < 8; ++ct)
#pragma unroll
                for (int r = 0; r < 4; ++r) {
                    int colk = ko + ct * 16 + m16;
                    int row  = qt * 64 + wave * 16 + quad * 4 + r;
                    if (colk > row) s[ct][r] = -16384.f;   // exp2 -> 0
                }
        }

        // p = exp2(s) directly; store bf16 P (transpose round-trip for A-frag)
#pragma unroll
        for (int ct = 0; ct < 8; ++ct)
#pragma unroll
            for (int r = 0; r < 4; ++r)
                Ps[wave * 16 + quad * 4 + r][ct * 16 + m16] =
                    f2bf(__builtin_exp2f(s[ct][r]));

        __asm__ volatile("s_waitcnt lgkmcnt(0)" ::: "memory");  // P visible

        bf16x8 pf[4];
#pragma unroll
        for (int kc = 0; kc < 4; ++kc)
            pf[kc] = *(const bf16x8*)&Ps[wave * 16 + m16][kc * 32 + quad * 8];
#pragma unroll
        for (int kc = 0; kc < 4; ++kc)
            lacc = __builtin_amdgcn_mfma_f32_16x16x32_bf16(pf[kc], ones8, lacc, 0, 0, 0);
#pragma unroll
        for (int ct = 0; ct < 4; ++ct) {
            const int vr = ct * 16 + m16;
#pragma unroll
            for (int kc = 0; kc < 4; ++kc) {
                bf16x8 vf = *(const bf16x8*)
                    &VsT[vr * 128 + (((kc * 4 + quad) ^ m16) * 8)];
                o[ct] = __builtin_amdgcn_mfma_f32_16x16x32_bf16(pf[kc], vf, o[ct], 0, 0, 0);
            }
        }
    }

    float inv[4];
#pragma unroll
    for (int r = 0; r < 4; ++r) inv[r] = 1.0f / lacc[r];
#pragma unroll
    for (int r = 0; r < 4; ++r) {
        int srow = qt * 64 + wave * 16 + quad * 4 + r;
        unsigned short* orow = O + (((size_t)b * S_LEN + srow) * NH + h) * DK;
#pragma unroll
        for (int ct = 0; ct < 4; ++ct)
            orow[ct * 16 + m16] = f2bf(o[ct][r] * inv[r]);
    }
}

// ---------------------------------------------------------------------------
extern "C" void kernel_launch(void* const* d_in, const int* in_sizes, int n_in,
                              void* d_out, int out_size, void* d_ws, size_t ws_size,
                              hipStream_t stream)
{
    const float* x      = (const float*)d_in[0];
    const float* Wq     = (const float*)d_in[1];
    const float* Wk     = (const float*)d_in[2];
    const float* Wv     = (const float*)d_in[3];
    const float* Wo     = (const float*)d_in[4];
    const float* cosT   = (const float*)d_in[5];
    const float* sinT   = (const float*)d_in[6];
    const int*   posArr = (const int*)d_in[7];
    float* out = (float*)d_out;

    unsigned short* ws0 = (unsigned short*)d_ws;
    unsigned short* Xb  = ws0;                 // 4,194,304 shorts
    unsigned short* Wb  = ws0 + 4194304;       // 3,145,728 ([Wq;Wk;Wv])
    unsigned short* Wob = ws0 + 7340032;       // 1,048,576
    unsigned short* Qw  = ws0 + 8388608;       // [bh][s][d]
    unsigned short* Kw  = ws0 + 12582912;      // [bh][s][d]
    unsigned short* Vtw = ws0 + 16777216;      // [bh][d][s]
    unsigned short* Ow  = ws0 + 20971520;      // [b][s][h][d]

    convert_bf16<<<8192, 256, 0, stream>>>(x, Wq, Wk, Wv, Wo, Xb, Wb, Wob);

    gemm_qkv<<<dim3(3072 / 128, 4096 / 128), 256, 0, stream>>>(
        Xb, Wb, cosT, sinT, posArr, Qw, Kw, Vtw);

    flash_mfma<<<1024, 256, 0, stream>>>(Qw, Kw, Vtw, Ow);

    gemm_proj<<<dim3(D_MODEL / 128, 4096 / 64), 256, 0, stream>>>(Ow, Wob, out);
}

// Round 16
// 183.524 us; speedup vs baseline: 1.1462x; 1.0618x over previous
//
#include <hip/hip_runtime.h>
#include <cstdint>
#include <cstddef>

#define D_MODEL 1024
#define NH 16
#define DK 64
#define S_LEN 2048
// M = B*S = 4096; QKV packed N = 3072

typedef __attribute__((ext_vector_type(8))) short bf16x8;
typedef __attribute__((ext_vector_type(4))) float f32x4;

#define QSCALE 0.1803368801111204f   // 0.125 * log2(e): exp2-domain softmax

__device__ __forceinline__ unsigned short f2bf(float f) {
    union { float f; unsigned int u; } v; v.f = f;
    unsigned int r = (v.u + 0x7fffu + ((v.u >> 16) & 1u)) >> 16;
    return (unsigned short)r;
}

// async global->LDS, 16B per lane; LDS dst is wave-uniform base + lane*16
#define GLL(g, l) __builtin_amdgcn_global_load_lds( \
    (const __attribute__((address_space(1))) unsigned int*)(g), \
    (__attribute__((address_space(3))) unsigned int*)(l), 16, 0, 0)

// ---------------------------------------------------------------------------
// Pre-pass: fp32 -> bf16 for x and all weights.
// ---------------------------------------------------------------------------
__global__ __launch_bounds__(256) void convert_bf16(
    const float* __restrict__ x,
    const float* __restrict__ wq, const float* __restrict__ wk,
    const float* __restrict__ wv, const float* __restrict__ wo,
    unsigned short* __restrict__ Xb, unsigned short* __restrict__ Wb,
    unsigned short* __restrict__ Wob)
{
    const unsigned t = blockIdx.x * 256 + threadIdx.x;  // float4 index
    const float* src;
    unsigned short* dst;
    if (t < 1048576u)      { src = x  + 4 * (size_t)t;               dst = Xb  + 4 * (size_t)t; }
    else if (t < 1310720u) { size_t i = t - 1048576u; src = wq + 4*i; dst = Wb + 4*i; }
    else if (t < 1572864u) { size_t i = t - 1310720u; src = wk + 4*i; dst = Wb + 1048576u + 4*i; }
    else if (t < 1835008u) { size_t i = t - 1572864u; src = wv + 4*i; dst = Wb + 2097152u + 4*i; }
    else                   { size_t i = t - 1835008u; src = wo + 4*i; dst = Wob + 4*i; }
    float4 v = *(const float4*)src;
    unsigned short pk[4] = {f2bf(v.x), f2bf(v.y), f2bf(v.z), f2bf(v.w)};
    *(uint2*)dst = *(const uint2*)pk;
}

// ---------------------------------------------------------------------------
// QKV: C = Xb(4096x1024) * Wb^T (Wb rows: [Wq;Wk;Wv]).
// 64x128 tile (M-split, r13 proj pattern) -> dbuf LDS 48 KB -> 3 blocks/CU
// (was 128x128 @ 64 KB = 2 blocks/CU). 4 waves as 2(M)x2(N), 2x4 acc/wave,
// A=2 GLL + B=4 GLL per stage, vmcnt(6). XOR-swizzled pitch-64; frag reads
// un-swizzle with ^(m16&7). RoPE epilogue via Cs overlay + coalesced out.
// ---------------------------------------------------------------------------
#define CP 132   // Cs pitch: 264 B
__global__ __launch_bounds__(256) void gemm_qkv(
    const unsigned short* __restrict__ Xb, const unsigned short* __restrict__ Wb,
    const float* __restrict__ cosT, const float* __restrict__ sinT,
    const int* __restrict__ posArr,
    unsigned short* __restrict__ Qo, unsigned short* __restrict__ Ko,
    unsigned short* __restrict__ Vt)
{
    __shared__ __align__(16) unsigned short smem[2 * 12288];  // 48 KB
    unsigned short* Cs = smem;   // epilogue overlay (64*CP = 8448 < 24576)

    const int tid  = threadIdx.x;
    const int wave = tid >> 6;
    const int lane = tid & 63;
    const int m16  = lane & 15;
    const int quad = lane >> 4;
    const int warpM = (wave >> 1) * 32;
    const int warpN = (wave & 1) * 64;
    const int rowBase = blockIdx.y * 64;
    const int colBase = blockIdx.x * 128;

    const int l8  = lane >> 3;
    const int lb  = lane & 7;
    const int cbl = (lb ^ l8) * 8;

    const unsigned short* Arow = Xb + (size_t)rowBase * D_MODEL;
    const unsigned short* Brow = Wb + (size_t)colBase * D_MODEL;

    f32x4 acc[2][4];
#pragma unroll
    for (int i = 0; i < 2; ++i)
#pragma unroll
        for (int j = 0; j < 4; ++j) acc[i][j] = (f32x4){0.f, 0.f, 0.f, 0.f};

    auto stage = [&](int k0, int bsel) {
        unsigned short* As = smem + bsel * 12288;   // 64x64
        unsigned short* Bs = As + 4096;             // 128x64
#pragma unroll
        for (int it = 0; it < 2; ++it) {            // A: 2 GLL
            const int r = wave * 16 + it * 8 + l8;
            GLL(Arow + (size_t)r * D_MODEL + k0 + cbl,
                &As[wave * 1024 + it * 512 + lane * 8]);
        }
#pragma unroll
        for (int it = 0; it < 4; ++it) {            // B: 4 GLL
            const int r = wave * 32 + it * 8 + l8;
            GLL(Brow + (size_t)r * D_MODEL + k0 + cbl,
                &Bs[wave * 2048 + it * 512 + lane * 8]);
        }
    };

    stage(0, 0);
    for (int it = 0; it < 16; ++it) {
        const int cur = it & 1;
        if (it < 15) {
            stage((it + 1) * 64, cur ^ 1);
            __asm__ volatile("s_waitcnt vmcnt(6)" ::: "memory");
        } else {
            __asm__ volatile("s_waitcnt vmcnt(0)" ::: "memory");
        }
        __syncthreads();
        const unsigned short* As = smem + cur * 12288;
        const unsigned short* Bs = As + 4096;
#pragma unroll
        for (int ks = 0; ks < 2; ++ks) {
            bf16x8 af[2], bf[4];
            const int cb = ((ks * 4 + quad) ^ (m16 & 7)) * 8;
#pragma unroll
            for (int t4 = 0; t4 < 2; ++t4)
                af[t4] = *(const bf16x8*)&As[(warpM + t4 * 16 + m16) * 64 + cb];
#pragma unroll
            for (int t4 = 0; t4 < 4; ++t4)
                bf[t4] = *(const bf16x8*)&Bs[(warpN + t4 * 16 + m16) * 64 + cb];
#pragma unroll
            for (int mt = 0; mt < 2; ++mt)
#pragma unroll
                for (int nt = 0; nt < 4; ++nt)
                    acc[mt][nt] = __builtin_amdgcn_mfma_f32_16x16x32_bf16(
                        af[mt], bf[nt], acc[mt][nt], 0, 0, 0);
        }
        __syncthreads();
    }

    // Epilogue. C/D: col = m16, row = quad*4+reg. Block cols lie entirely in
    // one of q/k/v (1024 % 128 == 0) -> `which` is block-uniform.
    const int which = (colBase + warpN) >> 10;   // 0=q,1=k,2=v
    if (which == 2) {
#pragma unroll
        for (int mt = 0; mt < 2; ++mt) {
            const int gr0 = rowBase + warpM + mt * 16 + quad * 4;
            const int b   = gr0 >> 11;
            const int s0  = gr0 & 2047;
#pragma unroll
            for (int nt = 0; nt < 4; ++nt) {
                const int c1 = (colBase + warpN + nt * 16 + m16) & 1023;
                const int h  = c1 >> 6;
                const int d  = c1 & 63;
                unsigned short pk[4];
#pragma unroll
                for (int r = 0; r < 4; ++r) pk[r] = f2bf(acc[mt][nt][r]);
                *(uint2*)(Vt + ((size_t)(b * NH + h) * DK + d) * S_LEN + s0) =
                    *(const uint2*)pk;
            }
        }
    } else {
        __syncthreads();   // staging reads done; reuse smem as Cs
#pragma unroll
        for (int mt = 0; mt < 2; ++mt) {
            const int lr0 = warpM + mt * 16 + quad * 4;  // local row 0..63
#pragma unroll
            for (int nt = 0; nt < 4; ++nt) {
                const int lc = warpN + nt * 16 + m16;    // local col 0..127
                const int d  = lc & 63;
#pragma unroll
                for (int r = 0; r < 4; ++r) {
                    const int s = (rowBase + lr0 + r) & 2047;
                    const int p = posArr[s];
                    float v = acc[mt][nt][r];
                    float o = __shfl_xor(v, 1, 64);
                    float c  = cosT[(size_t)p * DK + d];
                    float sn = sinT[(size_t)p * DK + d];
                    float res = (d & 1) ? (v * c + o * sn) : (v * c - o * sn);
                    if (which == 0) res *= QSCALE;
                    Cs[(lr0 + r) * CP + lc] = f2bf(res);
                }
            }
        }
        __syncthreads();
        // coalesced copy-out: thread -> one (row, 32-col quarter) = 64 B
        unsigned short* outB = (which == 0) ? Qo : Ko;
        const int row = tid >> 2;                 // 0..63
        const int qtr = tid & 3;                  // 0..3
        const int gr  = rowBase + row;
        const int b   = gr >> 11;
        const int s   = gr & 2047;
        const int h   = ((colBase & 1023) >> 6) + (qtr >> 1);
        const int d0  = (qtr & 1) * 32;
        unsigned short* dst = outB + ((size_t)(b * NH + h) * S_LEN + s) * DK + d0;
        const unsigned short* srcp = &Cs[row * CP + qtr * 32];
#pragma unroll
        for (int j = 0; j < 4; ++j)               // 4 x 16B = 64 B = 32 dims
            ((uint4*)dst)[j] = ((const uint4*)srcp)[j];
    }
}

// ---------------------------------------------------------------------------
// Out-projection: C = Ow(4096x1024 bf16) * Wob^T -> fp32 d_out.
// 64x128 tile (M-split) -> grid 512 = 2 blocks/CU. 4 waves as 2(M)x2(N),
// 2x4 acc tiles/wave, dbuf LDS 48 KB, vmcnt(6).
// ---------------------------------------------------------------------------
__global__ __launch_bounds__(256) void gemm_proj(
    const unsigned short* __restrict__ A, const unsigned short* __restrict__ B,
    float* __restrict__ C)
{
    __shared__ __align__(16) unsigned short smem[2 * 12288];  // 48 KB

    const int tid  = threadIdx.x;
    const int wave = tid >> 6;
    const int lane = tid & 63;
    const int m16  = lane & 15;
    const int quad = lane >> 4;
    const int warpM = (wave >> 1) * 32;
    const int warpN = (wave & 1) * 64;
    const int rowBase = blockIdx.y * 64;
    const int colBase = blockIdx.x * 128;

    const int l8  = lane >> 3;
    const int lb  = lane & 7;
    const int cbl = (lb ^ l8) * 8;

    const unsigned short* Arow = A + (size_t)rowBase * D_MODEL;
    const unsigned short* Brow = B + (size_t)colBase * D_MODEL;

    f32x4 acc[2][4];
#pragma unroll
    for (int i = 0; i < 2; ++i)
#pragma unroll
        for (int j = 0; j < 4; ++j) acc[i][j] = (f32x4){0.f, 0.f, 0.f, 0.f};

    auto stage = [&](int k0, int bsel) {
        unsigned short* As = smem + bsel * 12288;   // 64x64
        unsigned short* Bs = As + 4096;             // 128x64
#pragma unroll
        for (int it = 0; it < 2; ++it) {            // A: 2 GLL
            const int r = wave * 16 + it * 8 + l8;
            GLL(Arow + (size_t)r * D_MODEL + k0 + cbl,
                &As[wave * 1024 + it * 512 + lane * 8]);
        }
#pragma unroll
        for (int it = 0; it < 4; ++it) {            // B: 4 GLL
            const int r = wave * 32 + it * 8 + l8;
            GLL(Brow + (size_t)r * D_MODEL + k0 + cbl,
                &Bs[wave * 2048 + it * 512 + lane * 8]);
        }
    };

    stage(0, 0);
    for (int it = 0; it < 16; ++it) {
        const int cur = it & 1;
        if (it < 15) {
            stage((it + 1) * 64, cur ^ 1);
            __asm__ volatile("s_waitcnt vmcnt(6)" ::: "memory");
        } else {
            __asm__ volatile("s_waitcnt vmcnt(0)" ::: "memory");
        }
        __syncthreads();
        const unsigned short* As = smem + cur * 12288;
        const unsigned short* Bs = As + 4096;
#pragma unroll
        for (int ks = 0; ks < 2; ++ks) {
            bf16x8 af[2], bf[4];
            const int cb = ((ks * 4 + quad) ^ (m16 & 7)) * 8;
#pragma unroll
            for (int t4 = 0; t4 < 2; ++t4)
                af[t4] = *(const bf16x8*)&As[(warpM + t4 * 16 + m16) * 64 + cb];
#pragma unroll
            for (int t4 = 0; t4 < 4; ++t4)
                bf[t4] = *(const bf16x8*)&Bs[(warpN + t4 * 16 + m16) * 64 + cb];
#pragma unroll
            for (int mt = 0; mt < 2; ++mt)
#pragma unroll
                for (int nt = 0; nt < 4; ++nt)
                    acc[mt][nt] = __builtin_amdgcn_mfma_f32_16x16x32_bf16(
                        af[mt], bf[nt], acc[mt][nt], 0, 0, 0);
        }
        __syncthreads();
    }

#pragma unroll
    for (int mt = 0; mt < 2; ++mt)
#pragma unroll
        for (int reg = 0; reg < 4; ++reg) {
            int gr = rowBase + warpM + mt * 16 + quad * 4 + reg;
            float* crow = C + (size_t)gr * D_MODEL + colBase + warpN;
#pragma unroll
            for (int nt = 0; nt < 4; ++nt)
                crow[nt * 16 + m16] = acc[mt][nt][reg];
        }
}

// ---------------------------------------------------------------------------
// MFMA flash attention (round-13/15 version: best measured). Causal, bf16,
// exp2-domain (Q pre-scaled), no online max (scores bounded; uniform exp2
// offsets cancel in o/l). Q-tile 64 (4 waves), K-tile 128, GLL staging,
// XOR swizzle, l via ones-MFMA, separate Ps buffer (49.4 KB LDS, 3 blocks/CU
// — NOT the 32 KB overlay: launch_bounds(256,4) drove VGPR to 64 and spilled
// 50 MB to scratch, r14 regression).
// 1D grid: qt = 31-(g>>5) (big blocks first), bh = g&31 (head-per-XCD L2).
// ---------------------------------------------------------------------------
__global__ __launch_bounds__(256, 3) void flash_mfma(
    const unsigned short* __restrict__ Q,
    const unsigned short* __restrict__ K,
    const unsigned short* __restrict__ Vt,
    unsigned short* __restrict__ O)
{
    const int g    = blockIdx.x;
    const int qt   = 31 - (g >> 5);
    const int bh   = g & 31;
    const int b    = bh >> 4;
    const int h    = bh & 15;
    const int tid  = threadIdx.x;
    const int wave = tid >> 6;
    const int lane = tid & 63;
    const int m16  = lane & 15;
    const int quad = lane >> 4;
    const int l8   = lane >> 3;
    const int nIter = (qt >> 1) + 1;

    __shared__ __align__(16) unsigned short Ks[128 * 64];   // swizzled ^(r&7)
    __shared__ __align__(16) unsigned short VsT[64 * 128];  // [d][s], ^(d&15)
    __shared__ __align__(16) unsigned short Ps[64][136];

    // ---- stage Q tile into Ks rows 0..63 (same swizzle as K), grab frags
    const unsigned short* Qg = Q + ((size_t)bh * S_LEN + qt * 64) * DK;
#pragma unroll
    for (int it = 0; it < 2; ++it) {
        const int rb = wave * 16 + it * 8;
        const int r  = rb + l8;
        const int cb = ((lane & 7) ^ (r & 7)) * 8;
        GLL(Qg + r * DK + cb, &Ks[rb * 64 + lane * 8]);
    }
    __asm__ volatile("s_waitcnt vmcnt(0)" ::: "memory");
    __syncthreads();
    const int qrow = wave * 16 + m16;
    const bf16x8 qf0 = *(const bf16x8*)&Ks[qrow * 64 + ((quad ^ (m16 & 7)) * 8)];
    const bf16x8 qf1 = *(const bf16x8*)&Ks[qrow * 64 + (((4 + quad) ^ (m16 & 7)) * 8)];

    const short one_bf = (short)0x3F80;
    const bf16x8 ones8 = {one_bf, one_bf, one_bf, one_bf,
                          one_bf, one_bf, one_bf, one_bf};

    f32x4 o[4];
    f32x4 lacc = (f32x4){0.f, 0.f, 0.f, 0.f};
#pragma unroll
    for (int r = 0; r < 4; ++r) o[r] = (f32x4){0.f, 0.f, 0.f, 0.f};

    const unsigned short* Kg0 = K + (size_t)bh * S_LEN * DK;
    const unsigned short* Vg0 = Vt + (size_t)bh * DK * S_LEN;

    for (int kb = 0; kb < nIter; ++kb) {
        const int ko = kb * 128;
        __syncthreads();   // prior iter's frag reads (and Q preamble) complete
        // K tile: 128 rows x 64 cols, swizzle ^(r&7)
#pragma unroll
        for (int it = 0; it < 4; ++it) {
            const int rb = wave * 32 + it * 8;
            const int r  = rb + l8;
            const int cb = ((lane & 7) ^ (r & 7)) * 8;
            GLL(Kg0 + (size_t)(ko + r) * DK + cb, &Ks[rb * 64 + lane * 8]);
        }
        // V^T tile: 64 rows(d) x 128 cols(s), swizzle ^(d&15)
#pragma unroll
        for (int it = 0; it < 4; ++it) {
            const int db = wave * 16 + it * 4;
            const int d  = db + (lane >> 4);
            const int cb = ((lane & 15) ^ (d & 15)) * 8;
            GLL(Vg0 + (size_t)d * S_LEN + ko + cb, &VsT[db * 128 + lane * 8]);
        }
        __asm__ volatile("s_waitcnt vmcnt(0)" ::: "memory");
        __syncthreads();

        // S = Q*K^T : 16 rows x 128 keys per wave (8 n-tiles)
        f32x4 s[8];
#pragma unroll
        for (int ct = 0; ct < 8; ++ct) {
            const int kr = ct * 16 + m16;
            bf16x8 kf0 = *(const bf16x8*)&Ks[kr * 64 + ((quad ^ (m16 & 7)) * 8)];
            bf16x8 kf1 = *(const bf16x8*)&Ks[kr * 64 + (((4 + quad) ^ (m16 & 7)) * 8)];
            f32x4 z = {0.f, 0.f, 0.f, 0.f};
            z = __builtin_amdgcn_mfma_f32_16x16x32_bf16(qf0, kf0, z, 0, 0, 0);
            z = __builtin_amdgcn_mfma_f32_16x16x32_bf16(qf1, kf1, z, 0, 0, 0);
            s[ct] = z;
        }

        if (kb == nIter - 1) {   // causal mask on the diagonal tile
#pragma unroll
            for (int ct = 0; ct < 8; ++ct)
#pragma unroll
                for (int r = 0; r < 4; ++r) {
                    int colk = ko + ct * 16 + m16;
                    int row  = qt * 64 + wave * 16 + quad * 4 + r;
                    if (colk > row) s[ct][r] = -16384.f;   // exp2 -> 0
                }
        }

        // p = exp2(s) directly; store bf16 P (transpose round-trip for A-frag)
#pragma unroll
        for (int ct = 0; ct < 8; ++ct)
#pragma unroll
            for (int r = 0; r < 4; ++r)
                Ps[wave * 16 + quad * 4 + r][ct * 16 + m16] =
                    f2bf(__builtin_exp2f(s[ct][r]));

        __asm__ volatile("s_waitcnt lgkmcnt(0)" ::: "memory");  // P visible

        bf16x8 pf[4];
#pragma unroll
        for (int kc = 0; kc < 4; ++kc)
            pf[kc] = *(const bf16x8*)&Ps[wave * 16 + m16][kc * 32 + quad * 8];
#pragma unroll
        for (int kc = 0; kc < 4; ++kc)
            lacc = __builtin_amdgcn_mfma_f32_16x16x32_bf16(pf[kc], ones8, lacc, 0, 0, 0);
#pragma unroll
        for (int ct = 0; ct < 4; ++ct) {
            const int vr = ct * 16 + m16;
#pragma unroll
            for (int kc = 0; kc < 4; ++kc) {
                bf16x8 vf = *(const bf16x8*)
                    &VsT[vr * 128 + (((kc * 4 + quad) ^ m16) * 8)];
                o[ct] = __builtin_amdgcn_mfma_f32_16x16x32_bf16(pf[kc], vf, o[ct], 0, 0, 0);
            }
        }
    }

    float inv[4];
#pragma unroll
    for (int r = 0; r < 4; ++r) inv[r] = 1.0f / lacc[r];
#pragma unroll
    for (int r = 0; r < 4; ++r) {
        int srow = qt * 64 + wave * 16 + quad * 4 + r;
        unsigned short* orow = O + (((size_t)b * S_LEN + srow) * NH + h) * DK;
#pragma unroll
        for (int ct = 0; ct < 4; ++ct)
            orow[ct * 16 + m16] = f2bf(o[ct][r] * inv[r]);
    }
}

// ---------------------------------------------------------------------------
extern "C" void kernel_launch(void* const* d_in, const int* in_sizes, int n_in,
                              void* d_out, int out_size, void* d_ws, size_t ws_size,
                              hipStream_t stream)
{
    const float* x      = (const float*)d_in[0];
    const float* Wq     = (const float*)d_in[1];
    const float* Wk     = (const float*)d_in[2];
    const float* Wv     = (const float*)d_in[3];
    const float* Wo     = (const float*)d_in[4];
    const float* cosT   = (const float*)d_in[5];
    const float* sinT   = (const float*)d_in[6];
    const int*   posArr = (const int*)d_in[7];
    float* out = (float*)d_out;

    unsigned short* ws0 = (unsigned short*)d_ws;
    unsigned short* Xb  = ws0;                 // 4,194,304 shorts
    unsigned short* Wb  = ws0 + 4194304;       // 3,145,728 ([Wq;Wk;Wv])
    unsigned short* Wob = ws0 + 7340032;       // 1,048,576
    unsigned short* Qw  = ws0 + 8388608;       // [bh][s][d]
    unsigned short* Kw  = ws0 + 12582912;      // [bh][s][d]
    unsigned short* Vtw = ws0 + 16777216;      // [bh][d][s]
    unsigned short* Ow  = ws0 + 20971520;      // [b][s][h][d]

    convert_bf16<<<8192, 256, 0, stream>>>(x, Wq, Wk, Wv, Wo, Xb, Wb, Wob);

    gemm_qkv<<<dim3(3072 / 128, 4096 / 64), 256, 0, stream>>>(
        Xb, Wb, cosT, sinT, posArr, Qw, Kw, Vtw);

    flash_mfma<<<1024, 256, 0, stream>>>(Qw, Kw, Vtw, Ow);

    gemm_proj<<<dim3(D_MODEL / 128, 4096 / 64), 256, 0, stream>>>(Ow, Wob, out);
}

// Round 17
// 182.308 us; speedup vs baseline: 1.1539x; 1.0067x over previous
//
#include <hip/hip_runtime.h>
#include <cstdint>
#include <cstddef>

#define D_MODEL 1024
#define NH 16
#define DK 64
#define S_LEN 2048
// M = B*S = 4096; QKV packed N = 3072

typedef __attribute__((ext_vector_type(8))) short bf16x8;
typedef __attribute__((ext_vector_type(4))) float f32x4;

#define QSCALE 0.1803368801111204f   // 0.125 * log2(e): exp2-domain softmax

__device__ __forceinline__ unsigned short f2bf(float f) {
    union { float f; unsigned int u; } v; v.f = f;
    unsigned int r = (v.u + 0x7fffu + ((v.u >> 16) & 1u)) >> 16;
    return (unsigned short)r;
}
// truncating bf16 (1 ALU op vs 4): used only for P, where the downward bias
// cancels between o = sum(p*v) and l = sum(p).
__device__ __forceinline__ unsigned short f2bf_trunc(float f) {
    union { float f; unsigned int u; } v; v.f = f;
    return (unsigned short)(v.u >> 16);
}

// async global->LDS, 16B per lane; LDS dst is wave-uniform base + lane*16
#define GLL(g, l) __builtin_amdgcn_global_load_lds( \
    (const __attribute__((address_space(1))) unsigned int*)(g), \
    (__attribute__((address_space(3))) unsigned int*)(l), 16, 0, 0)

// ---------------------------------------------------------------------------
// Pre-pass: fp32 -> bf16 for x and all weights.
// ---------------------------------------------------------------------------
__global__ __launch_bounds__(256) void convert_bf16(
    const float* __restrict__ x,
    const float* __restrict__ wq, const float* __restrict__ wk,
    const float* __restrict__ wv, const float* __restrict__ wo,
    unsigned short* __restrict__ Xb, unsigned short* __restrict__ Wb,
    unsigned short* __restrict__ Wob)
{
    const unsigned t = blockIdx.x * 256 + threadIdx.x;  // float4 index
    const float* src;
    unsigned short* dst;
    if (t < 1048576u)      { src = x  + 4 * (size_t)t;               dst = Xb  + 4 * (size_t)t; }
    else if (t < 1310720u) { size_t i = t - 1048576u; src = wq + 4*i; dst = Wb + 4*i; }
    else if (t < 1572864u) { size_t i = t - 1310720u; src = wk + 4*i; dst = Wb + 1048576u + 4*i; }
    else if (t < 1835008u) { size_t i = t - 1572864u; src = wv + 4*i; dst = Wb + 2097152u + 4*i; }
    else                   { size_t i = t - 1835008u; src = wo + 4*i; dst = Wob + 4*i; }
    float4 v = *(const float4*)src;
    unsigned short pk[4] = {f2bf(v.x), f2bf(v.y), f2bf(v.z), f2bf(v.w)};
    *(uint2*)dst = *(const uint2*)pk;
}

// ---------------------------------------------------------------------------
// QKV: C = Xb(4096x1024) * Wb^T (Wb rows: [Wq;Wk;Wv]).
// 64x128 tile (M-split) -> dbuf LDS 48 KB -> 3 blocks/CU. 4 waves as
// 2(M)x2(N), 2x4 acc/wave, A=2 GLL + B=4 GLL per stage, vmcnt(6).
// XOR-swizzled pitch-64; frag reads un-swizzle with ^(m16&7).
// RoPE epilogue via Cs overlay + coalesced out.
// ---------------------------------------------------------------------------
#define CP 132   // Cs pitch: 264 B
__global__ __launch_bounds__(256) void gemm_qkv(
    const unsigned short* __restrict__ Xb, const unsigned short* __restrict__ Wb,
    const float* __restrict__ cosT, const float* __restrict__ sinT,
    const int* __restrict__ posArr,
    unsigned short* __restrict__ Qo, unsigned short* __restrict__ Ko,
    unsigned short* __restrict__ Vt)
{
    __shared__ __align__(16) unsigned short smem[2 * 12288];  // 48 KB
    unsigned short* Cs = smem;   // epilogue overlay (64*CP = 8448 < 24576)

    const int tid  = threadIdx.x;
    const int wave = tid >> 6;
    const int lane = tid & 63;
    const int m16  = lane & 15;
    const int quad = lane >> 4;
    const int warpM = (wave >> 1) * 32;
    const int warpN = (wave & 1) * 64;
    const int rowBase = blockIdx.y * 64;
    const int colBase = blockIdx.x * 128;

    const int l8  = lane >> 3;
    const int lb  = lane & 7;
    const int cbl = (lb ^ l8) * 8;

    const unsigned short* Arow = Xb + (size_t)rowBase * D_MODEL;
    const unsigned short* Brow = Wb + (size_t)colBase * D_MODEL;

    f32x4 acc[2][4];
#pragma unroll
    for (int i = 0; i < 2; ++i)
#pragma unroll
        for (int j = 0; j < 4; ++j) acc[i][j] = (f32x4){0.f, 0.f, 0.f, 0.f};

    auto stage = [&](int k0, int bsel) {
        unsigned short* As = smem + bsel * 12288;   // 64x64
        unsigned short* Bs = As + 4096;             // 128x64
#pragma unroll
        for (int it = 0; it < 2; ++it) {            // A: 2 GLL
            const int r = wave * 16 + it * 8 + l8;
            GLL(Arow + (size_t)r * D_MODEL + k0 + cbl,
                &As[wave * 1024 + it * 512 + lane * 8]);
        }
#pragma unroll
        for (int it = 0; it < 4; ++it) {            // B: 4 GLL
            const int r = wave * 32 + it * 8 + l8;
            GLL(Brow + (size_t)r * D_MODEL + k0 + cbl,
                &Bs[wave * 2048 + it * 512 + lane * 8]);
        }
    };

    stage(0, 0);
    for (int it = 0; it < 16; ++it) {
        const int cur = it & 1;
        if (it < 15) {
            stage((it + 1) * 64, cur ^ 1);
            __asm__ volatile("s_waitcnt vmcnt(6)" ::: "memory");
        } else {
            __asm__ volatile("s_waitcnt vmcnt(0)" ::: "memory");
        }
        __syncthreads();
        const unsigned short* As = smem + cur * 12288;
        const unsigned short* Bs = As + 4096;
#pragma unroll
        for (int ks = 0; ks < 2; ++ks) {
            bf16x8 af[2], bf[4];
            const int cb = ((ks * 4 + quad) ^ (m16 & 7)) * 8;
#pragma unroll
            for (int t4 = 0; t4 < 2; ++t4)
                af[t4] = *(const bf16x8*)&As[(warpM + t4 * 16 + m16) * 64 + cb];
#pragma unroll
            for (int t4 = 0; t4 < 4; ++t4)
                bf[t4] = *(const bf16x8*)&Bs[(warpN + t4 * 16 + m16) * 64 + cb];
#pragma unroll
            for (int mt = 0; mt < 2; ++mt)
#pragma unroll
                for (int nt = 0; nt < 4; ++nt)
                    acc[mt][nt] = __builtin_amdgcn_mfma_f32_16x16x32_bf16(
                        af[mt], bf[nt], acc[mt][nt], 0, 0, 0);
        }
        __syncthreads();
    }

    // Epilogue. C/D: col = m16, row = quad*4+reg. `which` is block-uniform.
    const int which = (colBase + warpN) >> 10;   // 0=q,1=k,2=v
    if (which == 2) {
#pragma unroll
        for (int mt = 0; mt < 2; ++mt) {
            const int gr0 = rowBase + warpM + mt * 16 + quad * 4;
            const int b   = gr0 >> 11;
            const int s0  = gr0 & 2047;
#pragma unroll
            for (int nt = 0; nt < 4; ++nt) {
                const int c1 = (colBase + warpN + nt * 16 + m16) & 1023;
                const int h  = c1 >> 6;
                const int d  = c1 & 63;
                unsigned short pk[4];
#pragma unroll
                for (int r = 0; r < 4; ++r) pk[r] = f2bf(acc[mt][nt][r]);
                *(uint2*)(Vt + ((size_t)(b * NH + h) * DK + d) * S_LEN + s0) =
                    *(const uint2*)pk;
            }
        }
    } else {
        __syncthreads();   // staging reads done; reuse smem as Cs
#pragma unroll
        for (int mt = 0; mt < 2; ++mt) {
            const int lr0 = warpM + mt * 16 + quad * 4;  // local row 0..63
#pragma unroll
            for (int nt = 0; nt < 4; ++nt) {
                const int lc = warpN + nt * 16 + m16;    // local col 0..127
                const int d  = lc & 63;
#pragma unroll
                for (int r = 0; r < 4; ++r) {
                    const int s = (rowBase + lr0 + r) & 2047;
                    const int p = posArr[s];
                    float v = acc[mt][nt][r];
                    float o = __shfl_xor(v, 1, 64);
                    float c  = cosT[(size_t)p * DK + d];
                    float sn = sinT[(size_t)p * DK + d];
                    float res = (d & 1) ? (v * c + o * sn) : (v * c - o * sn);
                    if (which == 0) res *= QSCALE;
                    Cs[(lr0 + r) * CP + lc] = f2bf(res);
                }
            }
        }
        __syncthreads();
        // coalesced copy-out: thread -> one (row, 32-col quarter) = 64 B
        unsigned short* outB = (which == 0) ? Qo : Ko;
        const int row = tid >> 2;                 // 0..63
        const int qtr = tid & 3;                  // 0..3
        const int gr  = rowBase + row;
        const int b   = gr >> 11;
        const int s   = gr & 2047;
        const int h   = ((colBase & 1023) >> 6) + (qtr >> 1);
        const int d0  = (qtr & 1) * 32;
        unsigned short* dst = outB + ((size_t)(b * NH + h) * S_LEN + s) * DK + d0;
        const unsigned short* srcp = &Cs[row * CP + qtr * 32];
#pragma unroll
        for (int j = 0; j < 4; ++j)               // 4 x 16B = 64 B = 32 dims
            ((uint4*)dst)[j] = ((const uint4*)srcp)[j];
    }
}

// ---------------------------------------------------------------------------
// Out-projection: C = Ow(4096x1024 bf16) * Wob^T -> fp32 d_out.
// 64x128 tile (M-split) -> grid 512 = 2 blocks/CU. dbuf LDS 48 KB, vmcnt(6).
// ---------------------------------------------------------------------------
__global__ __launch_bounds__(256) void gemm_proj(
    const unsigned short* __restrict__ A, const unsigned short* __restrict__ B,
    float* __restrict__ C)
{
    __shared__ __align__(16) unsigned short smem[2 * 12288];  // 48 KB

    const int tid  = threadIdx.x;
    const int wave = tid >> 6;
    const int lane = tid & 63;
    const int m16  = lane & 15;
    const int quad = lane >> 4;
    const int warpM = (wave >> 1) * 32;
    const int warpN = (wave & 1) * 64;
    const int rowBase = blockIdx.y * 64;
    const int colBase = blockIdx.x * 128;

    const int l8  = lane >> 3;
    const int lb  = lane & 7;
    const int cbl = (lb ^ l8) * 8;

    const unsigned short* Arow = A + (size_t)rowBase * D_MODEL;
    const unsigned short* Brow = B + (size_t)colBase * D_MODEL;

    f32x4 acc[2][4];
#pragma unroll
    for (int i = 0; i < 2; ++i)
#pragma unroll
        for (int j = 0; j < 4; ++j) acc[i][j] = (f32x4){0.f, 0.f, 0.f, 0.f};

    auto stage = [&](int k0, int bsel) {
        unsigned short* As = smem + bsel * 12288;   // 64x64
        unsigned short* Bs = As + 4096;             // 128x64
#pragma unroll
        for (int it = 0; it < 2; ++it) {
            const int r = wave * 16 + it * 8 + l8;
            GLL(Arow + (size_t)r * D_MODEL + k0 + cbl,
                &As[wave * 1024 + it * 512 + lane * 8]);
        }
#pragma unroll
        for (int it = 0; it < 4; ++it) {
            const int r = wave * 32 + it * 8 + l8;
            GLL(Brow + (size_t)r * D_MODEL + k0 + cbl,
                &Bs[wave * 2048 + it * 512 + lane * 8]);
        }
    };

    stage(0, 0);
    for (int it = 0; it < 16; ++it) {
        const int cur = it & 1;
        if (it < 15) {
            stage((it + 1) * 64, cur ^ 1);
            __asm__ volatile("s_waitcnt vmcnt(6)" ::: "memory");
        } else {
            __asm__ volatile("s_waitcnt vmcnt(0)" ::: "memory");
        }
        __syncthreads();
        const unsigned short* As = smem + cur * 12288;
        const unsigned short* Bs = As + 4096;
#pragma unroll
        for (int ks = 0; ks < 2; ++ks) {
            bf16x8 af[2], bf[4];
            const int cb = ((ks * 4 + quad) ^ (m16 & 7)) * 8;
#pragma unroll
            for (int t4 = 0; t4 < 2; ++t4)
                af[t4] = *(const bf16x8*)&As[(warpM + t4 * 16 + m16) * 64 + cb];
#pragma unroll
            for (int t4 = 0; t4 < 4; ++t4)
                bf[t4] = *(const bf16x8*)&Bs[(warpN + t4 * 16 + m16) * 64 + cb];
#pragma unroll
            for (int mt = 0; mt < 2; ++mt)
#pragma unroll
                for (int nt = 0; nt < 4; ++nt)
                    acc[mt][nt] = __builtin_amdgcn_mfma_f32_16x16x32_bf16(
                        af[mt], bf[nt], acc[mt][nt], 0, 0, 0);
        }
        __syncthreads();
    }

#pragma unroll
    for (int mt = 0; mt < 2; ++mt)
#pragma unroll
        for (int reg = 0; reg < 4; ++reg) {
            int gr = rowBase + warpM + mt * 16 + quad * 4 + reg;
            float* crow = C + (size_t)gr * D_MODEL + colBase + warpN;
#pragma unroll
            for (int nt = 0; nt < 4; ++nt)
                crow[nt * 16 + m16] = acc[mt][nt][reg];
        }
}

// ---------------------------------------------------------------------------
// MFMA flash attention (r13/r15 structure). Causal, bf16, exp2-domain
// (Q pre-scaled), no online max. Q-tile 64 (4 waves), K-tile 128, GLL
// staging, XOR swizzle, l via ones-MFMA, separate Ps buffer (49.4 KB,
// 3 blocks/CU). P packs with TRUNCATING bf16 (1 ALU op vs 4 for RNE;
// downward bias cancels between o and l) — flash is VALUBusy-dominated
// (46%, r16 counters) and the pack chain sits between QK^T and PV.
// 1D grid: qt = 31-(g>>5) (big blocks first), bh = g&31 (head-per-XCD L2).
// ---------------------------------------------------------------------------
__global__ __launch_bounds__(256, 3) void flash_mfma(
    const unsigned short* __restrict__ Q,
    const unsigned short* __restrict__ K,
    const unsigned short* __restrict__ Vt,
    unsigned short* __restrict__ O)
{
    const int g    = blockIdx.x;
    const int qt   = 31 - (g >> 5);
    const int bh   = g & 31;
    const int b    = bh >> 4;
    const int h    = bh & 15;
    const int tid  = threadIdx.x;
    const int wave = tid >> 6;
    const int lane = tid & 63;
    const int m16  = lane & 15;
    const int quad = lane >> 4;
    const int l8   = lane >> 3;
    const int nIter = (qt >> 1) + 1;

    __shared__ __align__(16) unsigned short Ks[128 * 64];   // swizzled ^(r&7)
    __shared__ __align__(16) unsigned short VsT[64 * 128];  // [d][s], ^(d&15)
    __shared__ __align__(16) unsigned short Ps[64][136];

    // ---- stage Q tile into Ks rows 0..63 (same swizzle as K), grab frags
    const unsigned short* Qg = Q + ((size_t)bh * S_LEN + qt * 64) * DK;
#pragma unroll
    for (int it = 0; it < 2; ++it) {
        const int rb = wave * 16 + it * 8;
        const int r  = rb + l8;
        const int cb = ((lane & 7) ^ (r & 7)) * 8;
        GLL(Qg + r * DK + cb, &Ks[rb * 64 + lane * 8]);
    }
    __asm__ volatile("s_waitcnt vmcnt(0)" ::: "memory");
    __syncthreads();
    const int qrow = wave * 16 + m16;
    const bf16x8 qf0 = *(const bf16x8*)&Ks[qrow * 64 + ((quad ^ (m16 & 7)) * 8)];
    const bf16x8 qf1 = *(const bf16x8*)&Ks[qrow * 64 + (((4 + quad) ^ (m16 & 7)) * 8)];

    const short one_bf = (short)0x3F80;
    const bf16x8 ones8 = {one_bf, one_bf, one_bf, one_bf,
                          one_bf, one_bf, one_bf, one_bf};

    f32x4 o[4];
    f32x4 lacc = (f32x4){0.f, 0.f, 0.f, 0.f};
#pragma unroll
    for (int r = 0; r < 4; ++r) o[r] = (f32x4){0.f, 0.f, 0.f, 0.f};

    const unsigned short* Kg0 = K + (size_t)bh * S_LEN * DK;
    const unsigned short* Vg0 = Vt + (size_t)bh * DK * S_LEN;

    for (int kb = 0; kb < nIter; ++kb) {
        const int ko = kb * 128;
        __syncthreads();   // prior iter's frag reads (and Q preamble) complete
        // K tile: 128 rows x 64 cols, swizzle ^(r&7)
#pragma unroll
        for (int it = 0; it < 4; ++it) {
            const int rb = wave * 32 + it * 8;
            const int r  = rb + l8;
            const int cb = ((lane & 7) ^ (r & 7)) * 8;
            GLL(Kg0 + (size_t)(ko + r) * DK + cb, &Ks[rb * 64 + lane * 8]);
        }
        // V^T tile: 64 rows(d) x 128 cols(s), swizzle ^(d&15)
#pragma unroll
        for (int it = 0; it < 4; ++it) {
            const int db = wave * 16 + it * 4;
            const int d  = db + (lane >> 4);
            const int cb = ((lane & 15) ^ (d & 15)) * 8;
            GLL(Vg0 + (size_t)d * S_LEN + ko + cb, &VsT[db * 128 + lane * 8]);
        }
        __asm__ volatile("s_waitcnt vmcnt(0)" ::: "memory");
        __syncthreads();

        // S = Q*K^T : 16 rows x 128 keys per wave (8 n-tiles)
        f32x4 s[8];
#pragma unroll
        for (int ct = 0; ct < 8; ++ct) {
            const int kr = ct * 16 + m16;
            bf16x8 kf0 = *(const bf16x8*)&Ks[kr * 64 + ((quad ^ (m16 & 7)) * 8)];
            bf16x8 kf1 = *(const bf16x8*)&Ks[kr * 64 + (((4 + quad) ^ (m16 & 7)) * 8)];
            f32x4 z = {0.f, 0.f, 0.f, 0.f};
            z = __builtin_amdgcn_mfma_f32_16x16x32_bf16(qf0, kf0, z, 0, 0, 0);
            z = __builtin_amdgcn_mfma_f32_16x16x32_bf16(qf1, kf1, z, 0, 0, 0);
            s[ct] = z;
        }

        if (kb == nIter - 1) {   // causal mask on the diagonal tile
#pragma unroll
            for (int ct = 0; ct < 8; ++ct)
#pragma unroll
                for (int r = 0; r < 4; ++r) {
                    int colk = ko + ct * 16 + m16;
                    int row  = qt * 64 + wave * 16 + quad * 4 + r;
                    if (colk > row) s[ct][r] = -16384.f;   // exp2 -> 0
                }
        }

        // p = exp2(s); truncating bf16 pack; P round-trip for A-frag layout
#pragma unroll
        for (int ct = 0; ct < 8; ++ct)
#pragma unroll
            for (int r = 0; r < 4; ++r)
                Ps[wave * 16 + quad * 4 + r][ct * 16 + m16] =
                    f2bf_trunc(__builtin_exp2f(s[ct][r]));

        __asm__ volatile("s_waitcnt lgkmcnt(0)" ::: "memory");  // P visible

        bf16x8 pf[4];
#pragma unroll
        for (int kc = 0; kc < 4; ++kc)
            pf[kc] = *(const bf16x8*)&Ps[wave * 16 + m16][kc * 32 + quad * 8];
#pragma unroll
        for (int kc = 0; kc < 4; ++kc)
            lacc = __builtin_amdgcn_mfma_f32_16x16x32_bf16(pf[kc], ones8, lacc, 0, 0, 0);
#pragma unroll
        for (int ct = 0; ct < 4; ++ct) {
            const int vr = ct * 16 + m16;
#pragma unroll
            for (int kc = 0; kc < 4; ++kc) {
                bf16x8 vf = *(const bf16x8*)
                    &VsT[vr * 128 + (((kc * 4 + quad) ^ m16) * 8)];
                o[ct] = __builtin_amdgcn_mfma_f32_16x16x32_bf16(pf[kc], vf, o[ct], 0, 0, 0);
            }
        }
    }

    float inv[4];
#pragma unroll
    for (int r = 0; r < 4; ++r) inv[r] = 1.0f / lacc[r];
#pragma unroll
    for (int r = 0; r < 4; ++r) {
        int srow = qt * 64 + wave * 16 + quad * 4 + r;
        unsigned short* orow = O + (((size_t)b * S_LEN + srow) * NH + h) * DK;
#pragma unroll
        for (int ct = 0; ct < 4; ++ct)
            orow[ct * 16 + m16] = f2bf(o[ct][r] * inv[r]);
    }
}

// ---------------------------------------------------------------------------
extern "C" void kernel_launch(void* const* d_in, const int* in_sizes, int n_in,
                              void* d_out, int out_size, void* d_ws, size_t ws_size,
                              hipStream_t stream)
{
    const float* x      = (const float*)d_in[0];
    const float* Wq     = (const float*)d_in[1];
    const float* Wk     = (const float*)d_in[2];
    const float* Wv     = (const float*)d_in[3];
    const float* Wo     = (const float*)d_in[4];
    const float* cosT   = (const float*)d_in[5];
    const float* sinT   = (const float*)d_in[6];
    const int*   posArr = (const int*)d_in[7];
    float* out = (float*)d_out;

    unsigned short* ws0 = (unsigned short*)d_ws;
    unsigned short* Xb  = ws0;                 // 4,194,304 shorts
    unsigned short* Wb  = ws0 + 4194304;       // 3,145,728 ([Wq;Wk;Wv])
    unsigned short* Wob = ws0 + 7340032;       // 1,048,576
    unsigned short* Qw  = ws0 + 8388608;       // [bh][s][d]
    unsigned short* Kw  = ws0 + 12582912;      // [bh][s][d]
    unsigned short* Vtw = ws0 + 16777216;      // [bh][d][s]
    unsigned short* Ow  = ws0 + 20971520;      // [b][s][h][d]

    convert_bf16<<<8192, 256, 0, stream>>>(x, Wq, Wk, Wv, Wo, Xb, Wb, Wob);

    gemm_qkv<<<dim3(3072 / 128, 4096 / 64), 256, 0, stream>>>(
        Xb, Wb, cosT, sinT, posArr, Qw, Kw, Vtw);

    flash_mfma<<<1024, 256, 0, stream>>>(Qw, Kw, Vtw, Ow);

    gemm_proj<<<dim3(D_MODEL / 128, 4096 / 64), 256, 0, stream>>>(Ow, Wob, out);
}